// Round 6
// baseline (162.041 us; speedup 1.0000x reference)
//
#include <hip/hip_runtime.h>
#include <stdint.h>

// FP4 quant-dequant, faithful to the JAX reference in float32 arithmetic.
// v6: k_scales occupancy fix. 32 blocks per wave (8 KB wave-private LDS
// slice, linear layout + rotated b128 reads), 2 lanes per block with a
// 5-shuffle pair merge. 32 KB LDS/WG -> 5 WG/CU, ~20 waves/CU (was 8).
// Per-element math identical to v5 (bit-exact).

#define BLK 64
#define WG 256
#define FLT_BIG 3.402823466e+38f

// Branchless insert of `a` into descending-sorted top-5 register array.
__device__ __forceinline__ void ins5(float (&t)[5], float a) {
#pragma unroll
    for (int k = 0; k < 4; ++k) {
        float m = fmaxf(t[k], a);
        a = fminf(t[k], a);
        t[k] = m;
    }
    t[4] = fmaxf(t[4], a);
}

// 4 * nearest FP4 level via boundary ladder (integers, exact).
// Equivalent to first-index argmin over the FP4 table: midpoints are exact
// dyadics; midpoint ties go to the lower-index level in both formulations.
__device__ __forceinline__ int qlvl4(float xn) {
    int bv = -12;
    bv += (xn > -2.5f)   ? 4 : 0;
    bv += (xn > -1.75f)  ? 2 : 0;
    bv += (xn > -1.25f)  ? 2 : 0;
    bv += (xn > -0.875f) ? 1 : 0;
    bv += (xn > -0.375f) ? 3 : 0;
    bv += (xn > 0.375f)  ? 3 : 0;
    bv += (xn > 0.875f)  ? 1 : 0;
    bv += (xn > 1.25f)   ? 2 : 0;
    bv += (xn > 1.75f)   ? 2 : 0;
    bv += (xn > 2.5f)    ? 4 : 0;
    return bv;
}

// Double-quantized scale, pre-divided by 4 (pairs with 4*level; /4 and *4 are
// exact power-of-two scalings => bit-identical to lvl*ds).
__device__ __forceinline__ float dscale4(float s, float smin, float smax) {
    if (smax > smin) {
        const float ss = __fdiv_rn(__fsub_rn(smax, smin), 255.0f);
        float q = rintf(__fdiv_rn(__fsub_rn(s, smin), ss));   // round half-even
        q = fminf(fmaxf(q, 0.0f), 255.0f);                    // clip AFTER round
        return __fmul_rn(q, ss) * 0.25f;
    }
    return 0.0f;   // q=0, scale_scale=1 -> deq 0
}

template <bool STORE_LEVELS>
__global__ __launch_bounds__(WG, 5) void k_scales(const float* __restrict__ x,
                                                  int n, int nblocks, int nwords,
                                                  float* __restrict__ scales,
                                                  uint32_t* __restrict__ levels,
                                                  uint32_t* __restrict__ hdr) {
    // 32 KB total: one 8 KB (512-float4) wave-private slice per wave.
    __shared__ float4 lds4[4 * 512];
    const int lane = threadIdx.x & 63;
    const int wv = threadIdx.x >> 6;
    float4* L4 = lds4 + wv * 512;
    uint32_t* Lw = reinterpret_cast<uint32_t*>(L4);

    const int batch = blockIdx.x * 4 + wv;      // 32 blocks per wave-batch
    const int blockBase = batch * 32;
    const bool waveActive = (blockBase < nblocks);
    const long eBase = (long)blockBase * BLK;

    const int b = lane >> 1;                     // local block 0..31
    const int h = lane & 1;                      // half: elements h*32..h*32+31
    const int myB = blockBase + b;
    const bool valid = waveActive && (myB < nblocks);

    // ---- Phase A: coalesced global -> linear LDS (wave-private) ----
    if (waveActive) {
        if (eBase + 2048 <= (long)n) {
            const float4* x4 = reinterpret_cast<const float4*>(x + eBase);
#pragma unroll
            for (int it = 0; it < 8; ++it)
                L4[it * 64 + lane] = x4[it * 64 + lane];
        } else {
            for (int it = 0; it < 8; ++it) {
                const int fi = it * 64 + lane;
                float tmp[4];
                for (int d = 0; d < 4; ++d) {
                    const long gi = eBase + (long)fi * 4 + d;
                    tmp[d] = (gi < (long)n) ? x[gi] : 0.0f;  // reference zero-pads
                }
                L4[fi] = make_float4(tmp[0], tmp[1], tmp[2], tmp[3]);
            }
        }
    }
    asm volatile("" ::: "memory");   // keep compiler from reordering LDS ops
    // Same-wave DS ops are in-order: no barrier needed for wave-private slice.

    // ---- Phase B: per-lane half-block math ----
    // Lane reads its 8 float4s with rotation ((j+b)&7): balanced bank quads.
    float4 v[8];
    if (waveActive) {
#pragma unroll
        for (int j = 0; j < 8; ++j)
            v[j] = L4[b * 16 + h * 8 + ((j + b) & 7)];
    } else {
#pragma unroll
        for (int j = 0; j < 8; ++j) v[j] = make_float4(0.f, 0.f, 0.f, 0.f);
    }

    float A[5] = {0.f, 0.f, 0.f, 0.f, 0.f};
    float B5[5] = {0.f, 0.f, 0.f, 0.f, 0.f};
#pragma unroll
    for (int j = 0; j < 8; j += 2) {
        ins5(A, fabsf(v[j].x));      ins5(B5, fabsf(v[j + 1].x));
        ins5(A, fabsf(v[j].y));      ins5(B5, fabsf(v[j + 1].y));
        ins5(A, fabsf(v[j].z));      ins5(B5, fabsf(v[j + 1].z));
        ins5(A, fabsf(v[j].w));      ins5(B5, fabsf(v[j + 1].w));
    }
#pragma unroll
    for (int k = 0; k < 5; ++k) ins5(A, B5[k]);

    // Pair merge: both lanes of (b) end with top-5 of the full 64 elements.
    float P[5];
#pragma unroll
    for (int k = 0; k < 5; ++k) P[k] = __shfl_xor(A[k], 1, 64);
#pragma unroll
    for (int k = 0; k < 5; ++k) ins5(A, P[k]);

    // JAX f32 quantile: q = 0.95f*63.0f; result = v59*lw + v60*hw
    const float qs = 0.95f * 63.0f;     // 59.849998474121094f
    const float hw = qs - 59.0f;
    const float lw = 60.0f - qs;
    float s = __fadd_rn(__fmul_rn(A[4], lw), __fmul_rn(A[3], hw));
    s = fmaxf(s, 1e-8f);
    if (valid && h == 0) scales[myB] = s;

    uint32_t plv[8];
    if (STORE_LEVELS && valid) {
#pragma unroll
        for (int j = 0; j < 8; ++j) {
            const int a0 = qlvl4(__fdiv_rn(v[j].x, s));
            const int a1 = qlvl4(__fdiv_rn(v[j].y, s));
            const int a2 = qlvl4(__fdiv_rn(v[j].z, s));
            const int a3 = qlvl4(__fdiv_rn(v[j].w, s));
            plv[j] = (uint32_t)(a0 & 255) | ((uint32_t)(a1 & 255) << 8) |
                     ((uint32_t)(a2 & 255) << 16) | ((uint32_t)(a3 & 255) << 24);
        }
    }

    // ---- Phase C: packed words -> LDS (same slot numbering) -> coalesced ----
    if (STORE_LEVELS && waveActive) {
        asm volatile("" ::: "memory");
        if (valid) {
#pragma unroll
            for (int j = 0; j < 8; ++j)
                Lw[b * 16 + h * 8 + ((j + b) & 7)] = plv[j];
        }
        asm volatile("" ::: "memory");
        const int wordBase = blockBase * 16;
#pragma unroll
        for (int m = 0; m < 2; ++m) {
            const int widx = m * 256 + lane * 4;
            const uint4 w = *reinterpret_cast<const uint4*>(Lw + widx);
            if (wordBase + widx + 3 < nwords) {
                *reinterpret_cast<uint4*>(levels + wordBase + widx) = w;
            } else {
                const uint32_t ws[4] = {w.x, w.y, w.z, w.w};
                for (int d = 0; d < 4; ++d)
                    if (wordBase + widx + d < nwords) levels[wordBase + widx + d] = ws[d];
            }
        }
    }

    // ---- Phase D: WG min/max of s -> atomics ----
    float mn = valid ? s : FLT_BIG;
    float mx = valid ? s : 0.0f;
#pragma unroll
    for (int off = 32; off > 0; off >>= 1) {
        mn = fminf(mn, __shfl_xor(mn, off, 64));
        mx = fmaxf(mx, __shfl_xor(mx, off, 64));
    }
    __syncthreads();                 // all waves done with their slices
    float* red = reinterpret_cast<float*>(lds4);
    if (lane == 0) { red[wv] = mn; red[4 + wv] = mx; }
    __syncthreads();
    if (threadIdx.x == 0) {
        float fmn = red[0], fmx = red[4];
#pragma unroll
        for (int i = 1; i < 4; ++i) { fmn = fminf(fmn, red[i]); fmx = fmaxf(fmx, red[4 + i]); }
        // uint order == float order for positive floats; s >= 1e-8 > 0.
        atomicMin(&hdr[0], __float_as_uint(fmn));
        atomicMax(&hdr[1], __float_as_uint(fmx));
    }
}

__global__ __launch_bounds__(WG) void k_deq(const uint32_t* __restrict__ levels,
                                            const float* __restrict__ scales,
                                            const uint32_t* __restrict__ hdr,
                                            int n, int nwords,
                                            float* __restrict__ out) {
    const int t = blockIdx.x * WG + threadIdx.x;
    if (t >= nwords) return;
    const float smin = __uint_as_float(hdr[0]);
    const float smax = __uint_as_float(hdr[1]);
    const float s = scales[t >> 4];
    const float ds4 = dscale4(s, smin, smax);

    const uint32_t wv = levels[t];
    const int i = t * 4;
    if (i + 3 < n) {
        float4 ov;
        ov.x = __fmul_rn((float)(int)(int8_t)(wv), ds4);
        ov.y = __fmul_rn((float)(int)(int8_t)(wv >> 8), ds4);
        ov.z = __fmul_rn((float)(int)(int8_t)(wv >> 16), ds4);
        ov.w = __fmul_rn((float)(int)(int8_t)(wv >> 24), ds4);
        *reinterpret_cast<float4*>(out + i) = ov;
    } else {
        for (int k = 0; k < 4 && i + k < n; ++k)
            out[i + k] = __fmul_rn((float)(int)(int8_t)(wv >> (8 * k)), ds4);
    }
}

// Fallback if ws can't hold the levels array: re-quantize from x.
__global__ __launch_bounds__(WG) void k_quant(const float* __restrict__ x,
                                              const float* __restrict__ scales,
                                              const uint32_t* __restrict__ hdr,
                                              int n,
                                              float* __restrict__ out) {
    const int t = blockIdx.x * WG + threadIdx.x;
    const int i = t * 4;
    if (i >= n) return;
    const float smin = __uint_as_float(hdr[0]);
    const float smax = __uint_as_float(hdr[1]);
    const float s = scales[i >> 6];
    const float ds4 = dscale4(s, smin, smax);

    if (i + 3 < n) {
        const float4 xv = *reinterpret_cast<const float4*>(x + i);
        float4 ov;
        ov.x = __fmul_rn((float)qlvl4(__fdiv_rn(xv.x, s)), ds4);
        ov.y = __fmul_rn((float)qlvl4(__fdiv_rn(xv.y, s)), ds4);
        ov.z = __fmul_rn((float)qlvl4(__fdiv_rn(xv.z, s)), ds4);
        ov.w = __fmul_rn((float)qlvl4(__fdiv_rn(xv.w, s)), ds4);
        *reinterpret_cast<float4*>(out + i) = ov;
    } else {
        for (int j = 0; j < 4 && i + j < n; ++j)
            out[i + j] = __fmul_rn((float)qlvl4(__fdiv_rn(x[i + j], s)), ds4);
    }
}

extern "C" void kernel_launch(void* const* d_in, const int* in_sizes, int n_in,
                              void* d_out, int out_size, void* d_ws, size_t ws_size,
                              hipStream_t stream) {
    const float* x = (const float*)d_in[0];
    float* out = (float*)d_out;
    const int n = in_sizes[0];
    const int nblocks = (n + BLK - 1) / BLK;
    const int nwords = nblocks * 16;                       // packed u32 words
    const int nwgScales = (nblocks + 127) / 128;           // 128 blocks per WG

    // ws layout: [hdr: 2 u32, padded to 16B] [scales: nblocks f32] [levels]
    uint32_t* hdr = (uint32_t*)d_ws;
    float* scales = (float*)((char*)d_ws + 16);
    uint32_t* levels = (uint32_t*)(scales + nblocks);
    const size_t need = 16 + (size_t)nblocks * 4 + (size_t)nwords * 4;
    const bool useLevels = (ws_size >= need);

    // hdr[0]=min init 0xFFFFFFFF (uint-max), hdr[1]=max init 0.
    hipMemsetAsync((void*)hdr, 0xFF, 4, stream);
    hipMemsetAsync((void*)((char*)d_ws + 4), 0x00, 4, stream);

    if (useLevels) {
        k_scales<true><<<nwgScales, WG, 0, stream>>>(x, n, nblocks, nwords, scales, levels, hdr);
        k_deq<<<(nwords + WG - 1) / WG, WG, 0, stream>>>(levels, scales, hdr, n, nwords, out);
    } else {
        k_scales<false><<<nwgScales, WG, 0, stream>>>(x, n, nblocks, nwords, scales, levels, hdr);
        k_quant<<<((n + 3) / 4 + WG - 1) / WG, WG, 0, stream>>>(x, scales, hdr, n, out);
    }
}